// Round 4
// baseline (240.604 us; speedup 1.0000x reference)
//
#include <hip/hip_runtime.h>

// SeaThru-NeRF RGB renderer forward pass, round 7 (= R6 with compile fix).
//
// R5 POST-MORTEM: removing all DS ops (DPP scans) changed nothing -- 96us,
// VALUBusy 18.7%, VGPR still 40. Three different structures = same time and
// same VGPR count. Diagnosis: the backend's pressure-minimizing scheduler
// SINKS every load to its use point (40 regs < 256 cap => no spills, just
// serialization). Per-wave MLP ~1 load in flight -> 18 waves/CU x 1KB / 900cyc
// ~= 1.8 TB/s -- exactly the measured HBM rate. We are MLP-bound by the
// compiler, not by hardware.
//
// FIX vs R5: liveness pins (empty asm volatile reading the loaded values)
// right after the load block. R6's single pin with float4 "v" operands hit
// "Don't know how to handle indirect register inputs yet" -- clang can't take
// 128-bit vectors in "v" constraints. So: one pin per float4, FOUR SCALAR
// operands each. volatile asm statements cannot reorder among themselves, so
// no load sinks past the pin block -> all 14 loads in flight, one vmcnt
// drain, all 56 floats live. Verify via VGPR_Count >> 40.

#define LOG2E 1.4426950408889634f

#define PIN4(v) asm volatile("" :: "v"((v).x), "v"((v).y), "v"((v).z), "v"((v).w))

__device__ __forceinline__ float clip01(float x) {
    return fminf(fmaxf(x, 0.0f), 1.0f);
}

// DPP move (old=0, bank_mask=0xf). Template params keep builtin args ICE.
template <int CTRL, int ROW_MASK, bool BND>
__device__ __forceinline__ float dpp_mov(float v) {
    return __int_as_float(__builtin_amdgcn_update_dpp(
        0, __float_as_int(v), CTRL, ROW_MASK, 0xf, BND));
}

// N-wide interleaved wave64 INCLUSIVE add-scan, entirely on the VALU pipe.
template <int N>
__device__ __forceinline__ void wave_iscan(float (&v)[N]) {
#pragma unroll
    for (int j = 0; j < N; ++j) v[j] += dpp_mov<0x111, 0xf, true>(v[j]);
#pragma unroll
    for (int j = 0; j < N; ++j) v[j] += dpp_mov<0x112, 0xf, true>(v[j]);
#pragma unroll
    for (int j = 0; j < N; ++j) v[j] += dpp_mov<0x114, 0xf, true>(v[j]);
#pragma unroll
    for (int j = 0; j < N; ++j) v[j] += dpp_mov<0x118, 0xf, true>(v[j]);
#pragma unroll
    for (int j = 0; j < N; ++j) v[j] += dpp_mov<0x142, 0xa, false>(v[j]);
#pragma unroll
    for (int j = 0; j < N; ++j) v[j] += dpp_mov<0x143, 0xc, false>(v[j]);
}

__global__ __launch_bounds__(256, 2) void seathru_render(
    const float* __restrict__ g_orgb,   // [R,S,3] object_rgbs
    const float* __restrict__ g_mrgb,   // [R,S,3] medium_rgbs
    const float* __restrict__ g_dc,     // [R,S,3] direct_coeffs
    const float* __restrict__ g_bc,     // [R,S,3] backscatter_coeffs
    const float* __restrict__ g_den,    // [R,S,1] densities
    const float* __restrict__ g_del,    // [R,S,1] deltas
    float* __restrict__ out, int R)
{
    const int S = 256;
    const int ray  = blockIdx.x * 4 + (threadIdx.x >> 6);  // wave-uniform
    const int lane = threadIdx.x & 63;
    if (ray >= R) return;

    const size_t b3 = (size_t)ray * (S * 3);
    const size_t b1 = (size_t)ray * S;
    const size_t RS = (size_t)R * S;

    // ---- issue ALL 14 loads; lane owns samples 4*lane .. 4*lane+3 ----
    const float4* pdc = (const float4*)(g_dc   + b3) + lane * 3;
    const float4* pbc = (const float4*)(g_bc   + b3) + lane * 3;
    const float4* por = (const float4*)(g_orgb + b3) + lane * 3;
    const float4* pmr = (const float4*)(g_mrgb + b3) + lane * 3;

    float4 dl4 = *((const float4*)(g_del + b1) + lane);
    float4 dn4 = *((const float4*)(g_den + b1) + lane);
    float4 dcA = pdc[0], dcB = pdc[1], dcC = pdc[2];
    float4 bcA = pbc[0], bcB = pbc[1], bcC = pbc[2];
    float4 orA = por[0], orB = por[1], orC = por[2];
    float4 mrA = pmr[0], mrB = pmr[1], mrC = pmr[2];

    // ---- LIVENESS PINS: volatile asms cannot reorder among themselves; no
    //      load sinks past its pin -> all 14 loads in flight together and all
    //      56 floats simultaneously register-live at this point.
    PIN4(dl4); PIN4(dn4);
    PIN4(dcA); PIN4(dcB); PIN4(dcC);
    PIN4(bcA); PIN4(bcB); PIN4(bcC);
    PIN4(orA); PIN4(orB); PIN4(orC);
    PIN4(mrA); PIN4(mrB); PIN4(mrC);

    // ---- unpack (static indices only; SROA keeps these in registers) ----
    const float dcv[12] = {dcA.x, dcA.y, dcA.z, dcA.w,
                           dcB.x, dcB.y, dcB.z, dcB.w,
                           dcC.x, dcC.y, dcC.z, dcC.w};
    const float bcv[12] = {bcA.x, bcA.y, bcA.z, bcA.w,
                           bcB.x, bcB.y, bcB.z, bcB.w,
                           bcC.x, bcC.y, bcC.z, bcC.w};
    const float orv[12] = {orA.x, orA.y, orA.z, orA.w,
                           orB.x, orB.y, orB.z, orB.w,
                           orC.x, orC.y, orC.z, orC.w};
    const float mrv[12] = {mrA.x, mrA.y, mrA.z, mrA.w,
                           mrB.x, mrB.y, mrB.z, mrB.w,
                           mrC.x, mrC.y, mrC.z, mrC.w};

    const float del[4] = {dl4.x * LOG2E, dl4.y * LOG2E, dl4.z * LOG2E, dl4.w * LOG2E};
    const float den[4] = {dn4.x, dn4.y, dn4.z, dn4.w};

    // ---- thread-local pre-pass ----
    float dd[4], alpha[4];
#pragma unroll
    for (int i = 0; i < 4; ++i) {
        dd[i]    = del[i] * den[i];
        alpha[i] = 1.0f - exp2f(-dd[i]);
    }

    float aorv[12];   // alpha * object_rgb
    float mamr[12];   // medium_alpha * medium_rgb
#pragma unroll
    for (int i = 0; i < 4; ++i) {
#pragma unroll
        for (int c = 0; c < 3; ++c) {
            aorv[i * 3 + c] = alpha[i] * orv[i * 3 + c];
            const float bsd = bcv[i * 3 + c] * del[i];
            mamr[i * 3 + c] = (1.0f - exp2f(-bsd)) * mrv[i * 3 + c];
        }
    }

    // ---- serial (intra-thread) exclusive prefixes for the 7 fused scans ----
    float ser[7][4];
    float run[7];
#pragma unroll
    for (int q = 0; q < 7; ++q) run[q] = 0.0f;
#pragma unroll
    for (int i = 0; i < 4; ++i) {
        ser[0][i] = run[0]; run[0] += dd[i];
#pragma unroll
        for (int c = 0; c < 3; ++c) {
            ser[1 + c][i] = run[1 + c]; run[1 + c] += dd[i] + dcv[i * 3 + c] * del[i];
            ser[4 + c][i] = run[4 + c]; run[4 + c] += dd[i] + bcv[i * 3 + c] * del[i];
        }
    }

    // ---- 7-wide interleaved DPP wave scan of the thread totals ----
    float sc[7];
#pragma unroll
    for (int q = 0; q < 7; ++q) sc[q] = run[q];
    wave_iscan<7>(sc);
    float off[7];
#pragma unroll
    for (int q = 0; q < 7; ++q) off[q] = sc[q] - run[q];   // wave-exclusive

    // ---- per-sample outputs ----
    float T[4], w[4];
#pragma unroll
    for (int i = 0; i < 4; ++i) {
        T[i] = exp2f(-(off[0] + ser[0][i]));
        w[i] = T[i] * alpha[i];
    }

    float* outT = out + (size_t)12 * R;      // object_transmittance [R,S]
    float* outA = outT + RS;                 // object_alphas
    float* outW = outA + RS;                 // object_weights
    {
        float4 t4 = {T[0], T[1], T[2], T[3]};
        float4 a4 = {alpha[0], alpha[1], alpha[2], alpha[3]};
        float4 w4 = {w[0], w[1], w[2], w[3]};
        *((float4*)(outT + b1) + lane) = t4;
        *((float4*)(outA + b1) + lane) = a4;
        *((float4*)(outW + b1) + lane) = w4;
    }

    // ---- per-thread contributions to the 10 per-ray sums ----
    float acc[10];
#pragma unroll
    for (int c = 0; c < 3; ++c) {
        float ad = 0.0f, ab = 0.0f, ar = 0.0f;
#pragma unroll
        for (int i = 0; i < 4; ++i) {
            ad += exp2f(-(off[1 + c] + ser[1 + c][i])) * aorv[i * 3 + c];
            ab += exp2f(-(off[4 + c] + ser[4 + c][i])) * mamr[i * 3 + c];
            ar += T[i] * aorv[i * 3 + c];
        }
        acc[c]     = ad;   // direct
        acc[3 + c] = ab;   // backscatter
        acc[6 + c] = ar;   // restored
    }
    acc[9] = w[0] + w[1] + w[2] + w[3];      // object mask

    // ---- 10-wide interleaved DPP reduction (lane 63 holds totals) ----
    wave_iscan<10>(acc);

    if (lane == 63) {
        float* rgb  = out;                                  // [R,3]
        float* rest = out + (size_t)3 * R;                  // [R,3]
        float* dir  = out + (size_t)6 * R;                  // [R,3]
        float* bs   = out + (size_t)9 * R;                  // [R,3]
        float* dc0  = out + (size_t)12 * R + 3 * RS;
        float* bc0  = dc0 + (size_t)3 * R;
        float* mask = bc0 + (size_t)3 * R;                  // [R,1]
#pragma unroll
        for (int c = 0; c < 3; ++c) {
            const float d = acc[c], b = acc[3 + c];
            rgb[ray * 3 + c]  = clip01(d + b);
            dir[ray * 3 + c]  = clip01(d);
            bs[ray * 3 + c]   = clip01(b);
            rest[ray * 3 + c] = clip01(acc[6 + c]);
        }
        mask[ray] = clip01(acc[9]);
    }
    if (lane == 0) {
        float* dc0 = out + (size_t)12 * R + 3 * RS;
        float* bc0 = dc0 + (size_t)3 * R;
#pragma unroll
        for (int c = 0; c < 3; ++c) {
            dc0[ray * 3 + c] = dcv[c];   // raw sample-0 coeffs (unscaled)
            bc0[ray * 3 + c] = bcv[c];
        }
    }
}

extern "C" void kernel_launch(void* const* d_in, const int* in_sizes, int n_in,
                              void* d_out, int out_size, void* d_ws, size_t ws_size,
                              hipStream_t stream) {
    const float* orgb = (const float*)d_in[0];
    const float* mrgb = (const float*)d_in[1];
    const float* dc   = (const float*)d_in[2];
    const float* bc   = (const float*)d_in[3];
    const float* den  = (const float*)d_in[4];
    const float* del  = (const float*)d_in[5];

    const int S = 256;
    const int R = in_sizes[0] / (S * 3);

    dim3 block(256);                 // 4 waves = 4 independent rays per block
    dim3 grid((R + 3) / 4);
    seathru_render<<<grid, block, 0, stream>>>(orgb, mrgb, dc, bc, den, del,
                                               (float*)d_out, R);
}